// Round 3
// baseline (380.477 us; speedup 1.0000x reference)
//
#include <hip/hip_runtime.h>
#include <math.h>

#define HSZ 8192
#define ISZ 4096
#define OSZ 4096
#define NTOT (HSZ + OSZ)
#define STEPS 100

__device__ __forceinline__ float bf2f(unsigned short h) {
    union { unsigned u; float f; } c; c.u = ((unsigned)h) << 16; return c.f;
}

__device__ __forceinline__ double compress_d(double x, double gain) {
    // sign(x) * log1p(gain*|x| + 1e-6), sign(0)==0
    double s = (x > 0.0) ? 1.0 : ((x < 0.0) ? -1.0 : 0.0);
    return s * log1p(gain * fabs(x) + 1e-6);
}

__device__ __forceinline__ double wred(double a) {
    #pragma unroll
    for (int o = 32; o > 0; o >>= 1) a += __shfl_down(a, o, 64);
    return a;
}

// W1 entries are U(0, 0.05). True bf16 data: every ushort is a bf16 in [0,0.05].
// fp32 data read as ushorts: every even ushort is a random low-mantissa half ->
// random exponent -> almost surely some |value| > 0.0625.
__global__ void detect_kernel(const void* W1, int* flag) {
    if (threadIdx.x == 0 && blockIdx.x == 0) {
        const unsigned short* p = (const unsigned short*)W1;
        int bf = 1;
        for (int i = 0; i < 128; ++i) {
            unsigned short a = (unsigned short)(p[i] & 0x7FFF);
            if (a > 0x3D80) bf = 0;   // |bf16(a)| > 0.0625
        }
        *flag = bf;
    }
}

// One wave per row, 4 rows / 256-thread block. Exact f64 dot -> compress -> fp32.
// XIN=1: x has input dtype (branch with flag); XIN=0: x is internal fp32.
template <int C, int XIN>
__global__ void mv_compress(const void* __restrict__ W, const void* __restrict__ x,
                            const void* __restrict__ gain, float* __restrict__ y,
                            const int* __restrict__ flag) {
    const int wave = threadIdx.x >> 6, lane = threadIdx.x & 63;
    const int row = blockIdx.x * 4 + wave;
    const int bf = *flag;
    double acc = 0.0;
    if (bf) {
        const ushort4* Wr = (const ushort4*)((const unsigned short*)W + (size_t)row * C);
        if (XIN) {
            const ushort4* xv = (const ushort4*)x;
            for (int it = 0; it < C / 256; ++it) {
                const int i = it * 64 + lane;
                ushort4 w = Wr[i], xx = xv[i];
                acc += (double)bf2f(w.x) * (double)bf2f(xx.x);
                acc += (double)bf2f(w.y) * (double)bf2f(xx.y);
                acc += (double)bf2f(w.z) * (double)bf2f(xx.z);
                acc += (double)bf2f(w.w) * (double)bf2f(xx.w);
            }
        } else {
            const float4* xv = (const float4*)x;
            for (int it = 0; it < C / 256; ++it) {
                const int i = it * 64 + lane;
                ushort4 w = Wr[i]; float4 xx = xv[i];
                acc += (double)bf2f(w.x) * (double)xx.x;
                acc += (double)bf2f(w.y) * (double)xx.y;
                acc += (double)bf2f(w.z) * (double)xx.z;
                acc += (double)bf2f(w.w) * (double)xx.w;
            }
        }
    } else {
        const float4* Wr = (const float4*)((const float*)W + (size_t)row * C);
        const float4* xv = (const float4*)x;   // fp32 either way when !bf
        for (int it = 0; it < C / 256; ++it) {
            const int i = it * 64 + lane;
            float4 w = Wr[i], xx = xv[i];
            acc += (double)w.x * (double)xx.x;
            acc += (double)w.y * (double)xx.y;
            acc += (double)w.z * (double)xx.z;
            acc += (double)w.w * (double)xx.w;
        }
    }
    acc = wred(acc);
    if (lane == 0) {
        float g = bf ? bf2f(*(const unsigned short*)gain) : *(const float*)gain;
        y[row] = (float)compress_d(acc, (double)g);
    }
}

// hid[r] = h1c[r] - Wfb[r,:]·io   (io is internal fp32; Wfb input dtype)
__global__ void mv_feedback(const void* __restrict__ Wfb, const float* __restrict__ io,
                            const float* __restrict__ h1c, float* __restrict__ hid,
                            const int* __restrict__ flag) {
    const int wave = threadIdx.x >> 6, lane = threadIdx.x & 63;
    const int row = blockIdx.x * 4 + wave;
    const int bf = *flag;
    double acc = 0.0;
    const float4* xv = (const float4*)io;
    if (bf) {
        const ushort4* Wr = (const ushort4*)((const unsigned short*)Wfb + (size_t)row * OSZ);
        for (int it = 0; it < OSZ / 256; ++it) {
            const int i = it * 64 + lane;
            ushort4 w = Wr[i]; float4 xx = xv[i];
            acc += (double)bf2f(w.x) * (double)xx.x;
            acc += (double)bf2f(w.y) * (double)xx.y;
            acc += (double)bf2f(w.z) * (double)xx.z;
            acc += (double)bf2f(w.w) * (double)xx.w;
        }
    } else {
        const float4* Wr = (const float4*)((const float*)Wfb + (size_t)row * OSZ);
        for (int it = 0; it < OSZ / 256; ++it) {
            const int i = it * 64 + lane;
            float4 w = Wr[i], xx = xv[i];
            acc += (double)w.x * (double)xx.x;
            acc += (double)w.y * (double)xx.y;
            acc += (double)w.z * (double)xx.z;
            acc += (double)w.w * (double)xx.w;
        }
    }
    acc = wred(acc);
    if (lane == 0) hid[row] = h1c[row] - (float)acc;
}

// loss = mean((io - target)^2); target has input dtype
__global__ void loss_kernel(const float* __restrict__ io, const void* __restrict__ tgt,
                            float* __restrict__ out, const int* __restrict__ flag) {
    __shared__ double red[4];
    const int bf = *flag;
    double acc = 0.0;
    for (int i = threadIdx.x; i < OSZ; i += 256) {
        float t = bf ? bf2f(((const unsigned short*)tgt)[i]) : ((const float*)tgt)[i];
        double d = (double)io[i] - (double)t;
        acc += d * d;
    }
    acc = wred(acc);
    if ((threadIdx.x & 63) == 0) red[threadIdx.x >> 6] = acc;
    __syncthreads();
    if (threadIdx.x == 0)
        out[0] = (float)((red[0] + red[1] + red[2] + red[3]) / (double)OSZ);
}

// fp32 Euler loop mirroring jax's op order exactly.
__global__ void sim_kernel(const float* __restrict__ hid, const float* __restrict__ io,
                           float* __restrict__ vout, float* __restrict__ uout) {
    const int n = blockIdx.x * blockDim.x + threadIdx.x;
    if (n >= NTOT) return;
    const float ti = (n < HSZ) ? hid[n] : io[n - HSZ];
    float v = -65.0f;
    float u = 0.2f * v;           // exactly -13.0f
    vout[n] = v;
    uout[n] = u;
    for (int s = 1; s < STEPS; ++s) {
        // v_prev + DT*(((((0.04*v^2) + 5.0*v) + 0.14) - u) + ti)
        float dv = 0.04f * (v * v);
        dv = dv + 5.0f * v;
        dv = dv + 0.14f;
        dv = dv - u;
        dv = dv + ti;
        float vn = v + 1.0f * dv;
        // u_prev + (DT*A)*(B*v_prev - u_prev)
        float du = 0.2f * v - u;
        float un = u + 0.02f * du;
        bool sp = (vn >= 30.0f);
        v = sp ? -65.0f : vn;
        u = sp ? (un + 8.0f) : un;
        vout[(size_t)s * NTOT + n] = v;
        uout[(size_t)s * NTOT + n] = u;
    }
}

extern "C" void kernel_launch(void* const* d_in, const int* in_sizes, int n_in,
                              void* d_out, int out_size, void* d_ws, size_t ws_size,
                              hipStream_t stream) {
    const void* v_input = d_in[0];
    const void* target  = d_in[1];
    const void* W1      = d_in[2];
    const void* W2      = d_in[3];
    const void* Wfb     = d_in[4];
    const void* gain1   = d_in[5];
    const void* gain2   = d_in[6];

    float* out  = (float*)d_out;
    float* vout = out + 1;
    float* uout = out + 1 + (size_t)STEPS * NTOT;

    int*   flag = (int*)d_ws;
    float* base = (float*)((char*)d_ws + 256);
    float* h1c  = base;           // [HSZ]
    float* io   = base + HSZ;     // [OSZ]
    float* hid  = io + OSZ;       // [HSZ]

    detect_kernel<<<1, 64, 0, stream>>>(W1, flag);
    mv_compress<ISZ, 1><<<HSZ / 4, 256, 0, stream>>>(W1, v_input, gain1, h1c, flag);
    mv_compress<HSZ, 0><<<OSZ / 4, 256, 0, stream>>>(W2, h1c, gain2, io, flag);
    mv_feedback<<<HSZ / 4, 256, 0, stream>>>(Wfb, io, h1c, hid, flag);
    loss_kernel<<<1, 256, 0, stream>>>(io, target, out, flag);
    sim_kernel<<<NTOT / 256, 256, 0, stream>>>(hid, io, vout, uout);
}